// Round 2
// baseline (107.412 us; speedup 1.0000x reference)
//
#include <hip/hip_runtime.h>

#define B_DIM 1024
#define C_DIM 256
#define EPS 1e-8f
#define LAMBDA_LPR 0.1f

// ws layout: acc[0] = bce sum, acc[1] = pair softplus sum, acc_u[2] = pair count (uint32)

__global__ __launch_bounds__(256) void spa_lpr_kernel(const float* __restrict__ logits,
                                                      const float* __restrict__ targets,
                                                      float* __restrict__ acc) {
    __shared__ float probs_s[C_DIM];
    __shared__ float t_s[C_DIM];
    __shared__ float r0[4], r1[4], r2[4];

    const int row = blockIdx.x;
    const int j = threadIdx.x;

    const float x = logits[row * C_DIM + j];
    const float t = targets[row * C_DIM + j];
    const float p = 1.0f / (1.0f + expf(-x));

    probs_s[j] = p;
    t_s[j] = t;

    // element-wise BCE (SPA) term — 256K evals total, keep precise libm
    float bce = -t * logf(p + EPS) - (1.0f - t) * logf(1.0f - p + EPS);

    __syncthreads();

    // pairwise softplus: this thread is the "pos" index p; scan all n.
    // weight = t[p] * (1 - t[n])  (exact 0/1 mask, no divergence).
    // d in (-1,1) so exp(d) in [0.37, 2.72]: safe for fast hw exp/log.
    float pairacc = 0.0f;
    const float tp = t;
    #pragma unroll 8
    for (int n = 0; n < C_DIM; ++n) {
        const float w = tp * (1.0f - t_s[n]);
        const float d = probs_s[n] - p;        // probs[i,n] - probs[i,p]
        pairacc += w * __logf(1.0f + __expf(d));
    }

    // block reduction: pairacc, bce, t (for npos)
    float tsum = t;
    #pragma unroll
    for (int off = 32; off > 0; off >>= 1) {
        pairacc += __shfl_down(pairacc, off);
        bce     += __shfl_down(bce, off);
        tsum    += __shfl_down(tsum, off);
    }
    const int lane = j & 63;
    const int wave = j >> 6;
    if (lane == 0) { r0[wave] = pairacc; r1[wave] = bce; r2[wave] = tsum; }
    __syncthreads();
    if (j == 0) {
        const float ps = r0[0] + r0[1] + r0[2] + r0[3];
        const float bs = r1[0] + r1[1] + r1[2] + r1[3];
        const float ts = r2[0] + r2[1] + r2[2] + r2[3];
        atomicAdd(&acc[0], bs);
        atomicAdd(&acc[1], ps);
        const unsigned int npos = (unsigned int)(ts + 0.5f);
        atomicAdd((unsigned int*)&acc[2], npos * ((unsigned int)C_DIM - npos));
    }
}

__global__ void finalize_kernel(const float* __restrict__ acc, float* __restrict__ out) {
    const float spa = acc[0] / (float)(B_DIM * C_DIM);
    const unsigned int cnt = ((const unsigned int*)acc)[2];
    const float lpr = acc[1] / ((float)cnt + EPS);
    out[0] = spa + LAMBDA_LPR * lpr;
}

extern "C" void kernel_launch(void* const* d_in, const int* in_sizes, int n_in,
                              void* d_out, int out_size, void* d_ws, size_t ws_size,
                              hipStream_t stream) {
    const float* logits  = (const float*)d_in[0];
    const float* targets = (const float*)d_in[1];
    float* out = (float*)d_out;
    float* acc = (float*)d_ws;

    // zero the 3-word accumulator (ws is re-poisoned to 0xAA before every launch)
    hipMemsetAsync(acc, 0, 3 * sizeof(float), stream);

    spa_lpr_kernel<<<B_DIM, 256, 0, stream>>>(logits, targets, acc);
    finalize_kernel<<<1, 1, 0, stream>>>(acc, out);
}